// Round 1
// baseline (532.588 us; speedup 1.0000x reference)
//
#include <hip/hip_runtime.h>
#include <math.h>

#define N_NODES 50000
#define N_EDGES 600000
#define DIM 128
#define KGAM 8
#define EPSV 1e-9f

// ---------------- utility ----------------
__global__ void k_zero_int(int* __restrict__ p, int n) {
    int i = blockIdx.x * blockDim.x + threadIdx.x;
    if (i < n) p[i] = 0;
}

__global__ void k_deg(const int* __restrict__ dst, int* __restrict__ deg) {
    int e = blockIdx.x * blockDim.x + threadIdx.x;
    if (e < N_EDGES) atomicAdd(&deg[dst[e]], 1);
}

// per-1024-chunk exclusive scan into rowstart (local), chunk totals, plus norm
__global__ void k_scan1(const int* __restrict__ deg, int* __restrict__ rowstart,
                        int* __restrict__ bsums, float* __restrict__ norm) {
    __shared__ int s[256];
    int tid = threadIdx.x;
    int i0 = blockIdx.x * 1024 + tid * 4;
    int v[4]; int sum = 0;
#pragma unroll
    for (int c = 0; c < 4; ++c) {
        int i = i0 + c;
        int d = (i < N_NODES) ? deg[i] : 0;
        v[c] = d; sum += d;
    }
    s[tid] = sum; __syncthreads();
#pragma unroll
    for (int off = 1; off < 256; off <<= 1) {
        int t = (tid >= off) ? s[tid - off] : 0;
        __syncthreads();
        s[tid] += t;
        __syncthreads();
    }
    if (tid == 255) bsums[blockIdx.x] = s[255];
    int run = s[tid] - sum;  // exclusive within chunk
#pragma unroll
    for (int c = 0; c < 4; ++c) {
        int i = i0 + c;
        if (i < N_NODES) {
            rowstart[i] = run;
            norm[i] = rsqrtf((float)(v[c] < 1 ? 1 : v[c]));
        }
        run += v[c];
    }
}

__global__ void k_scan2(int* __restrict__ bsums, int nb) {
    __shared__ int s[64];
    int tid = threadIdx.x;
    int v = (tid < nb) ? bsums[tid] : 0;
    s[tid] = v; __syncthreads();
#pragma unroll
    for (int off = 1; off < 64; off <<= 1) {
        int t = (tid >= off) ? s[tid - off] : 0;
        __syncthreads();
        s[tid] += t;
        __syncthreads();
    }
    if (tid < nb) bsums[tid] = s[tid] - v;  // exclusive
}

__global__ void k_scan3(const int* __restrict__ bsums, int* __restrict__ rowstart) {
    int i = blockIdx.x * blockDim.x + threadIdx.x;
    if (i < N_NODES) rowstart[i] += bsums[i >> 10];
    if (i == 0) rowstart[N_NODES] = N_EDGES;
}

__global__ void k_fill(const int* __restrict__ src, const int* __restrict__ dst,
                       const int* __restrict__ rowstart, int* __restrict__ cnt,
                       int* __restrict__ esrc) {
    int e = blockIdx.x * blockDim.x + threadIdx.x;
    if (e < N_EDGES) {
        int d = dst[e];
        int slot = rowstart[d] + atomicAdd(&cnt[d], 1);
        esrc[slot] = src[e];
    }
}

// out[v,:] = norm[v] * sum_{u in adj(v)} in[u,:]*norm[u]   (one wave per v)
__global__ void k_spmm(const float* __restrict__ in, const float* __restrict__ norm,
                       const int* __restrict__ rowstart, const int* __restrict__ esrc,
                       float* __restrict__ out) {
    int gid = blockIdx.x * blockDim.x + threadIdx.x;
    int wv = gid >> 6;
    int lane = threadIdx.x & 63;
    if (wv >= N_NODES) return;
    int beg = rowstart[wv], end = rowstart[wv + 1];
    float ax = 0.f, ay = 0.f;
    for (int t = beg; t < end; ++t) {
        int u = esrc[t];
        float nu = norm[u];
        const float2 f = *(const float2*)(in + (size_t)u * DIM + lane * 2);
        ax = fmaf(f.x, nu, ax);
        ay = fmaf(f.y, nu, ay);
    }
    float nv = norm[wv];
    float2 r; r.x = ax * nv; r.y = ay * nv;
    *(float2*)(out + (size_t)wv * DIM + lane * 2) = r;
}

// scalar blend coefficients from gammas (device-side, no host sync)
__global__ void k_coeffs(const float* __restrict__ gl, const float* __restrict__ gh,
                         const float* __restrict__ gm, float* __restrict__ c) {
    if (threadIdx.x == 0 && blockIdx.x == 0) {
        float a0 = 0, b0 = 0, a1 = 0, b1 = 0, sg = 0, m2 = 0;
        for (int k = 0; k < KGAM; ++k) {
            float al = EPSV + (float)k * (1.f - 2.f * EPSV) / (KGAM - 1);
            float md = EPSV + (float)k * (1.f - EPSV) / (KGAM - 1);
            float l = fmaxf(gl[k], 0.f), h = fmaxf(gh[k], 0.f), m = fmaxf(gm[k], 0.f);
            a0 += al * l;  b0 += (1.f - al) * l;
            a1 += -al * h; b1 += (1.f - al) * h;
            sg += m;       m2 += md * m;
        }
        c[0] = a0; c[1] = b0; c[2] = a1; c[3] = b1; c[4] = sg; c[5] = -m2;
    }
}

// ---------------- GEMM: out[n, j0:j0+64] = (ca*A + cf*F)[n,:] @ W[j0:j0+64,:]^T
#define RT 64
#define JT 64
#define WS_STRIDE 68   // JT+4: b128 reads conflict-free, staging writes 8-way (one-time)
#define TS_STRIDE 129  // DIM+1: broadcast reads conflict-free

__device__ __forceinline__ float sigm(float x) { return 1.f / (1.f + __expf(-x)); }

__global__ __launch_bounds__(256) void k_gemm(
    const float* __restrict__ A, const float* __restrict__ F,
    const float* __restrict__ W, const float* __restrict__ coeffs,
    int cia, int cif, float* __restrict__ out) {
    __shared__ float Ws[DIM * WS_STRIDE];
    __shared__ float Ts[RT * TS_STRIDE];
    float ca = coeffs[cia], cf = coeffs[cif];
    int j0 = blockIdx.y * JT;
    int r0 = blockIdx.x * RT;
    int tid = threadIdx.x;
    for (int i = tid; i < JT * DIM; i += 256) {
        int jj = i >> 7, k = i & 127;
        Ws[k * WS_STRIDE + jj] = W[(size_t)(j0 + jj) * DIM + k];
    }
    for (int i = tid; i < RT * DIM; i += 256) {
        int r = i >> 7, k = i & 127;
        int row = r0 + r;
        float t = 0.f;
        if (row < N_NODES) {
            size_t idx = (size_t)row * DIM + k;
            t = ca * A[idx] + cf * F[idx];
        }
        Ts[r * TS_STRIDE + k] = t;
    }
    __syncthreads();
    int tx = tid & 15, ty = tid >> 4;
    float acc[4][4] = {};
#pragma unroll 4
    for (int k = 0; k < DIM; ++k) {
        float4 w = *(const float4*)&Ws[k * WS_STRIDE + tx * 4];
#pragma unroll
        for (int r = 0; r < 4; ++r) {
            float t = Ts[(ty * 4 + r) * TS_STRIDE + k];
            acc[r][0] = fmaf(t, w.x, acc[r][0]);
            acc[r][1] = fmaf(t, w.y, acc[r][1]);
            acc[r][2] = fmaf(t, w.z, acc[r][2]);
            acc[r][3] = fmaf(t, w.w, acc[r][3]);
        }
    }
#pragma unroll
    for (int r = 0; r < 4; ++r) {
        int row = r0 + ty * 4 + r;
        if (row < N_NODES) {
            float4 o; o.x = acc[r][0]; o.y = acc[r][1]; o.z = acc[r][2]; o.w = acc[r][3];
            *(float4*)(out + (size_t)row * DIM + j0 + tx * 4) = o;
        }
    }
}

// third GEMM (o2) with fused sequential gating + bias + graph-norm + relu epilogue
__global__ __launch_bounds__(256) void k_gemm_mid_gate(
    const float* __restrict__ A, const float* __restrict__ F,
    const float* __restrict__ W, const float* __restrict__ coeffs,
    const float* __restrict__ o0b, const float* __restrict__ o1b,
    const float* __restrict__ bias, const float* __restrict__ snorm,
    float* __restrict__ out) {
    __shared__ float Ws[DIM * WS_STRIDE];
    __shared__ float Ts[RT * TS_STRIDE];
    float ca = coeffs[4], cf = coeffs[5];
    int j0 = blockIdx.y * JT;
    int r0 = blockIdx.x * RT;
    int tid = threadIdx.x;
    for (int i = tid; i < JT * DIM; i += 256) {
        int jj = i >> 7, k = i & 127;
        Ws[k * WS_STRIDE + jj] = W[(size_t)(j0 + jj) * DIM + k];
    }
    for (int i = tid; i < RT * DIM; i += 256) {
        int r = i >> 7, k = i & 127;
        int row = r0 + r;
        float t = 0.f;
        if (row < N_NODES) {
            size_t idx = (size_t)row * DIM + k;
            t = ca * A[idx] + cf * F[idx];
        }
        Ts[r * TS_STRIDE + k] = t;
    }
    __syncthreads();
    int tx = tid & 15, ty = tid >> 4;
    float acc[4][4] = {};
#pragma unroll 4
    for (int k = 0; k < DIM; ++k) {
        float4 w = *(const float4*)&Ws[k * WS_STRIDE + tx * 4];
#pragma unroll
        for (int r = 0; r < 4; ++r) {
            float t = Ts[(ty * 4 + r) * TS_STRIDE + k];
            acc[r][0] = fmaf(t, w.x, acc[r][0]);
            acc[r][1] = fmaf(t, w.y, acc[r][1]);
            acc[r][2] = fmaf(t, w.z, acc[r][2]);
            acc[r][3] = fmaf(t, w.w, acc[r][3]);
        }
    }
    float4 bb = *(const float4*)(bias + j0 + tx * 4);
#pragma unroll
    for (int r = 0; r < 4; ++r) {
        int row = r0 + ty * 4 + r;
        if (row < N_NODES) {
            size_t base = (size_t)row * DIM + j0 + tx * 4;
            float4 z0 = *(const float4*)(o0b + base);
            float4 z1 = *(const float4*)(o1b + base);
            float sn = snorm[row];
            float ov[4];
            float zz0[4] = {z0.x, z0.y, z0.z, z0.w};
            float zz1[4] = {z1.x, z1.y, z1.z, z1.w};
            float bv[4] = {bb.x, bb.y, bb.z, bb.w};
#pragma unroll
            for (int c = 0; c < 4; ++c) {
                float a2 = acc[r][c];
                float g0 = zz0[c] * sigm(zz1[c] + a2);
                float g1 = zz1[c] * sigm(g0 + a2);
                float g2 = a2 * sigm(g0 + g1);
                float v = (g0 + g1 + g2 + bv[c]) * sn;
                ov[c] = fmaxf(v, 0.f);
            }
            float4 o; o.x = ov[0]; o.y = ov[1]; o.z = ov[2]; o.w = ov[3];
            *(float4*)(out + base) = o;
        }
    }
}

extern "C" void kernel_launch(void* const* d_in, const int* in_sizes, int n_in,
                              void* d_out, int out_size, void* d_ws, size_t ws_size,
                              hipStream_t stream) {
    const float* feature = (const float*)d_in[0];
    const float* snorm   = (const float*)d_in[1];
    const int*   src     = (const int*)d_in[2];
    const int*   dst     = (const int*)d_in[3];
    const float* W_low   = (const float*)d_in[4];
    const float* W_high  = (const float*)d_in[5];
    const float* W_mid   = (const float*)d_in[6];
    const float* gl      = (const float*)d_in[7];
    const float* gh      = (const float*)d_in[8];
    const float* gm      = (const float*)d_in[9];
    const float* bias    = (const float*)d_in[10];
    float* out = (float*)d_out;

    char* w = (char*)d_ws;
    auto alloc = [&](size_t bytes) {
        char* p = w;
        w += (bytes + 255) & ~(size_t)255;
        return p;
    };
    float* norm   = (float*)alloc((size_t)N_NODES * 4);
    int* deg      = (int*)alloc((size_t)2 * N_NODES * 4);  // deg + cnt contiguous
    int* cnt      = deg + N_NODES;
    int* rowstart = (int*)alloc((size_t)(N_NODES + 1) * 4);
    int* bsums    = (int*)alloc(64 * 4);
    int* esrc     = (int*)alloc((size_t)N_EDGES * 4);
    float* coeffs = (float*)alloc(64 * 4);
    float* h      = (float*)alloc((size_t)N_NODES * DIM * 4);
    float* h1     = (float*)alloc((size_t)N_NODES * DIM * 4);
    float* o0b    = (float*)alloc((size_t)N_NODES * DIM * 4);
    float* o1b    = (float*)alloc((size_t)N_NODES * DIM * 4);

    k_zero_int<<<(2 * N_NODES + 255) / 256, 256, 0, stream>>>(deg, 2 * N_NODES);
    k_deg<<<(N_EDGES + 255) / 256, 256, 0, stream>>>(dst, deg);
    int nchunks = (N_NODES + 1023) / 1024;  // 49
    k_scan1<<<nchunks, 256, 0, stream>>>(deg, rowstart, bsums, norm);
    k_scan2<<<1, 64, 0, stream>>>(bsums, nchunks);
    k_scan3<<<(N_NODES + 255) / 256, 256, 0, stream>>>(bsums, rowstart);
    k_fill<<<(N_EDGES + 255) / 256, 256, 0, stream>>>(src, dst, rowstart, cnt, esrc);
    k_coeffs<<<1, 1, 0, stream>>>(gl, gh, gm, coeffs);

    int spmm_blocks = (N_NODES * 64 + 255) / 256;
    k_spmm<<<spmm_blocks, 256, 0, stream>>>(feature, norm, rowstart, esrc, h);
    k_spmm<<<spmm_blocks, 256, 0, stream>>>(h, norm, rowstart, esrc, h1);

    dim3 g((N_NODES + RT - 1) / RT, DIM / JT);
    k_gemm<<<g, 256, 0, stream>>>(h, feature, W_low, coeffs, 0, 1, o0b);
    k_gemm<<<g, 256, 0, stream>>>(h, feature, W_high, coeffs, 2, 3, o1b);
    k_gemm_mid_gate<<<g, 256, 0, stream>>>(h1, feature, W_mid, coeffs,
                                           o0b, o1b, bias, snorm, out);
}

// Round 2
// 327.904 us; speedup vs baseline: 1.6242x; 1.6242x over previous
//
#include <hip/hip_runtime.h>
#include <hip/hip_bf16.h>
#include <math.h>

#define N_NODES 50000
#define N_EDGES 600000
#define DIM 128
#define KGAM 8
#define EPSV 1e-9f

typedef __attribute__((ext_vector_type(8))) short short8;
typedef __attribute__((ext_vector_type(4))) short short4v;
typedef __attribute__((ext_vector_type(4))) float float4v;

__device__ __forceinline__ short f2bf(float f) {
    __hip_bfloat16 h = __float2bfloat16(f);
    return __builtin_bit_cast(short, h);
}
__device__ __forceinline__ float sigm(float x) { return 1.f / (1.f + __expf(-x)); }

// ---------------- CSR build ----------------
__global__ void k_zero_int(int* __restrict__ p, int n) {
    int i = blockIdx.x * blockDim.x + threadIdx.x;
    if (i < n) p[i] = 0;
}

__global__ void k_deg(const int* __restrict__ dst, int* __restrict__ deg) {
    int e = blockIdx.x * blockDim.x + threadIdx.x;
    if (e < N_EDGES) atomicAdd(&deg[dst[e]], 1);
}

__global__ void k_scan1(const int* __restrict__ deg, int* __restrict__ rowstart,
                        int* __restrict__ bsums, float* __restrict__ norm) {
    __shared__ int s[256];
    int tid = threadIdx.x;
    int i0 = blockIdx.x * 1024 + tid * 4;
    int v[4]; int sum = 0;
#pragma unroll
    for (int c = 0; c < 4; ++c) {
        int i = i0 + c;
        int d = (i < N_NODES) ? deg[i] : 0;
        v[c] = d; sum += d;
    }
    s[tid] = sum; __syncthreads();
#pragma unroll
    for (int off = 1; off < 256; off <<= 1) {
        int t = (tid >= off) ? s[tid - off] : 0;
        __syncthreads();
        s[tid] += t;
        __syncthreads();
    }
    if (tid == 255) bsums[blockIdx.x] = s[255];
    int run = s[tid] - sum;
#pragma unroll
    for (int c = 0; c < 4; ++c) {
        int i = i0 + c;
        if (i < N_NODES) {
            rowstart[i] = run;
            norm[i] = rsqrtf((float)(v[c] < 1 ? 1 : v[c]));
        }
        run += v[c];
    }
}

__global__ void k_scan2(int* __restrict__ bsums, int nb) {
    __shared__ int s[64];
    int tid = threadIdx.x;
    int v = (tid < nb) ? bsums[tid] : 0;
    s[tid] = v; __syncthreads();
#pragma unroll
    for (int off = 1; off < 64; off <<= 1) {
        int t = (tid >= off) ? s[tid - off] : 0;
        __syncthreads();
        s[tid] += t;
        __syncthreads();
    }
    if (tid < nb) bsums[tid] = s[tid] - v;
}

__global__ void k_scan3(const int* __restrict__ bsums, int* __restrict__ rowstart) {
    int i = blockIdx.x * blockDim.x + threadIdx.x;
    if (i < N_NODES) rowstart[i] += bsums[i >> 10];
    if (i == 0) rowstart[N_NODES] = N_EDGES;
}

__global__ void k_fill(const int* __restrict__ src, const int* __restrict__ dst,
                       const int* __restrict__ rowstart, int* __restrict__ cnt,
                       int* __restrict__ esrc) {
    int e = blockIdx.x * blockDim.x + threadIdx.x;
    if (e < N_EDGES) {
        int d = dst[e];
        int slot = rowstart[d] + atomicAdd(&cnt[d], 1);
        esrc[slot] = src[e];
    }
}

// ---------------- SpMM: one wave per dst node, unroll-4 for MLP ----------------
__global__ void k_spmm(const float* __restrict__ in, const float* __restrict__ norm,
                       const int* __restrict__ rowstart, const int* __restrict__ esrc,
                       float* __restrict__ out) {
    int gid = blockIdx.x * blockDim.x + threadIdx.x;
    int wv = gid >> 6;
    int lane = threadIdx.x & 63;
    if (wv >= N_NODES) return;
    int beg = rowstart[wv], end = rowstart[wv + 1];
    float ax = 0.f, ay = 0.f;
    int t = beg;
    for (; t + 3 < end; t += 4) {
        int u0 = esrc[t], u1 = esrc[t + 1], u2 = esrc[t + 2], u3 = esrc[t + 3];
        const float2 f0 = *(const float2*)(in + (size_t)u0 * DIM + lane * 2);
        const float2 f1 = *(const float2*)(in + (size_t)u1 * DIM + lane * 2);
        const float2 f2 = *(const float2*)(in + (size_t)u2 * DIM + lane * 2);
        const float2 f3 = *(const float2*)(in + (size_t)u3 * DIM + lane * 2);
        float n0 = norm[u0], n1 = norm[u1], n2 = norm[u2], n3 = norm[u3];
        ax = fmaf(f0.x, n0, fmaf(f1.x, n1, fmaf(f2.x, n2, fmaf(f3.x, n3, ax))));
        ay = fmaf(f0.y, n0, fmaf(f1.y, n1, fmaf(f2.y, n2, fmaf(f3.y, n3, ay))));
    }
    for (; t < end; ++t) {
        int u = esrc[t];
        float nu = norm[u];
        const float2 f = *(const float2*)(in + (size_t)u * DIM + lane * 2);
        ax = fmaf(f.x, nu, ax);
        ay = fmaf(f.y, nu, ay);
    }
    float nv = norm[wv];
    float2 r; r.x = ax * nv; r.y = ay * nv;
    *(float2*)(out + (size_t)wv * DIM + lane * 2) = r;
}

// ---------------- blend coefficients (device-side) ----------------
__global__ void k_coeffs(const float* __restrict__ gl, const float* __restrict__ gh,
                         const float* __restrict__ gm, float* __restrict__ c) {
    if (threadIdx.x == 0 && blockIdx.x == 0) {
        float a0 = 0, b0 = 0, a1 = 0, b1 = 0, sg = 0, m2 = 0;
        for (int k = 0; k < KGAM; ++k) {
            float al = EPSV + (float)k * (1.f - 2.f * EPSV) / (KGAM - 1);
            float md = EPSV + (float)k * (1.f - EPSV) / (KGAM - 1);
            float l = fmaxf(gl[k], 0.f), h = fmaxf(gh[k], 0.f), m = fmaxf(gm[k], 0.f);
            a0 += al * l;  b0 += (1.f - al) * l;
            a1 += -al * h; b1 += (1.f - al) * h;
            sg += m;       m2 += md * m;
        }
        c[0] = a0; c[1] = b0; c[2] = a1; c[3] = b1; c[4] = sg; c[5] = -m2;
    }
}

// ---------------- weights -> bf16 (once per launch; Wb is 3x128x128) ----------------
__global__ void k_wconv(const float* __restrict__ W0, const float* __restrict__ W1,
                        const float* __restrict__ W2, short* __restrict__ Wb) {
    const float* Ws = (blockIdx.y == 0) ? W0 : (blockIdx.y == 1) ? W1 : W2;
    int i = (blockIdx.x * 256 + threadIdx.x) * 4;
    if (i < DIM * DIM) {
        float4 v = *(const float4*)(Ws + i);
        short4v s;
        s[0] = f2bf(v.x); s[1] = f2bf(v.y); s[2] = f2bf(v.z); s[3] = f2bf(v.w);
        *(short4v*)(Wb + blockIdx.y * DIM * DIM + i) = s;
    }
}

// ---------------- fused tri-GEMM + gating epilogue ----------------
// out[r,:] for all 3 GEMMs in one pass over h/f/h1; bf16 MFMA 16x16x32.
// Verified fragment mappings (learn_hip m89/m118/m120):
//   A: lane holds A[m=lane&15][k=quad*8+j]  (16B contiguous along k)
//   B: lane holds W[n=lane&15 row][k=quad*8+j] for out = T @ W^T
//   C/D: col=lane&15, row=quad*4+reg
#define RT 64
#define TSTR 136   // bf16 stride: pad 128->136 to break power-of-2 banks

__global__ __launch_bounds__(256, 3) void k_gemm_fused(
    const float* __restrict__ h, const float* __restrict__ f,
    const float* __restrict__ h1, const short* __restrict__ Wb,
    const float* __restrict__ coeffs, const float* __restrict__ bias,
    const float* __restrict__ snorm, float* __restrict__ out) {
    __shared__ short Ts[3][RT * TSTR];

    const float c0 = coeffs[0], c1 = coeffs[1], c2 = coeffs[2];
    const float c3 = coeffs[3], c4 = coeffs[4], c5 = coeffs[5];
    const int r0 = blockIdx.x * RT;
    const int tid = threadIdx.x;

    // stage: blend h/f/h1 -> bf16 T0,T1,T2 tiles
#pragma unroll
    for (int it = 0; it < 8; ++it) {
        int idx = tid + it * 256;          // 0..2047
        int r = idx >> 5;                  // 0..63
        int cg = (idx & 31) * 4;           // col group of 4
        int row = r0 + r;
        float4 hv = {0, 0, 0, 0}, fv = {0, 0, 0, 0}, h1v = {0, 0, 0, 0};
        if (row < N_NODES) {
            size_t base = (size_t)row * DIM + cg;
            hv  = *(const float4*)(h + base);
            fv  = *(const float4*)(f + base);
            h1v = *(const float4*)(h1 + base);
        }
        short4v t0, t1, t2;
        t0[0] = f2bf(c0 * hv.x + c1 * fv.x); t0[1] = f2bf(c0 * hv.y + c1 * fv.y);
        t0[2] = f2bf(c0 * hv.z + c1 * fv.z); t0[3] = f2bf(c0 * hv.w + c1 * fv.w);
        t1[0] = f2bf(c2 * hv.x + c3 * fv.x); t1[1] = f2bf(c2 * hv.y + c3 * fv.y);
        t1[2] = f2bf(c2 * hv.z + c3 * fv.z); t1[3] = f2bf(c2 * hv.w + c3 * fv.w);
        t2[0] = f2bf(c4 * h1v.x + c5 * fv.x); t2[1] = f2bf(c4 * h1v.y + c5 * fv.y);
        t2[2] = f2bf(c4 * h1v.z + c5 * fv.z); t2[3] = f2bf(c4 * h1v.w + c5 * fv.w);
        int la = r * TSTR + cg;
        *(short4v*)&Ts[0][la] = t0;
        *(short4v*)&Ts[1][la] = t1;
        *(short4v*)&Ts[2][la] = t2;
    }
    __syncthreads();

    const int lane = tid & 63;
    const int wv = tid >> 6;        // 0..3 -> row sub-tile
    const int m = lane & 15;
    const int quad = lane >> 4;
    const int arow = wv * 16 + m;

    float4v acc[3][8];
    const float4v zero = {0.f, 0.f, 0.f, 0.f};
#pragma unroll
    for (int g = 0; g < 3; ++g)
#pragma unroll
        for (int ct = 0; ct < 8; ++ct) acc[g][ct] = zero;

#pragma unroll
    for (int ks = 0; ks < 4; ++ks) {
        int aoff = arow * TSTR + ks * 32 + quad * 8;
        short8 a0 = *(const short8*)&Ts[0][aoff];
        short8 a1 = *(const short8*)&Ts[1][aoff];
        short8 a2 = *(const short8*)&Ts[2][aoff];
        int boff = m * DIM + ks * 32 + quad * 8;
#pragma unroll
        for (int ct = 0; ct < 8; ++ct) {
            const short* wp = Wb + ct * 16 * DIM + boff;
            short8 b0 = *(const short8*)(wp);
            short8 b1 = *(const short8*)(wp + DIM * DIM);
            short8 b2 = *(const short8*)(wp + 2 * DIM * DIM);
            acc[0][ct] = __builtin_amdgcn_mfma_f32_16x16x32_bf16(a0, b0, acc[0][ct], 0, 0, 0);
            acc[1][ct] = __builtin_amdgcn_mfma_f32_16x16x32_bf16(a1, b1, acc[1][ct], 0, 0, 0);
            acc[2][ct] = __builtin_amdgcn_mfma_f32_16x16x32_bf16(a2, b2, acc[2][ct], 0, 0, 0);
        }
    }

    // epilogue: sequential mutual gating + bias + graph-norm + relu
    float sn[4];
#pragma unroll
    for (int r = 0; r < 4; ++r) {
        int row = r0 + wv * 16 + quad * 4 + r;
        sn[r] = (row < N_NODES) ? snorm[row] : 0.f;
    }
#pragma unroll
    for (int ct = 0; ct < 8; ++ct) {
        int col = ct * 16 + m;
        float bc = bias[col];
        float4v v0 = acc[0][ct], v1 = acc[1][ct], v2 = acc[2][ct];
#pragma unroll
        for (int r = 0; r < 4; ++r) {
            int row = r0 + wv * 16 + quad * 4 + r;
            if (row < N_NODES) {
                float o0 = v0[r], o1 = v1[r], o2 = v2[r];
                float g0 = o0 * sigm(o1 + o2);
                float g1 = o1 * sigm(g0 + o2);
                float g2 = o2 * sigm(g0 + g1);
                float v = (g0 + g1 + g2 + bc) * sn[r];
                out[(size_t)row * DIM + col] = fmaxf(v, 0.f);
            }
        }
    }
}

extern "C" void kernel_launch(void* const* d_in, const int* in_sizes, int n_in,
                              void* d_out, int out_size, void* d_ws, size_t ws_size,
                              hipStream_t stream) {
    const float* feature = (const float*)d_in[0];
    const float* snorm   = (const float*)d_in[1];
    const int*   src     = (const int*)d_in[2];
    const int*   dst     = (const int*)d_in[3];
    const float* W_low   = (const float*)d_in[4];
    const float* W_high  = (const float*)d_in[5];
    const float* W_mid   = (const float*)d_in[6];
    const float* gl      = (const float*)d_in[7];
    const float* gh      = (const float*)d_in[8];
    const float* gm      = (const float*)d_in[9];
    const float* bias    = (const float*)d_in[10];
    float* out = (float*)d_out;

    char* w = (char*)d_ws;
    auto alloc = [&](size_t bytes) {
        char* p = w;
        w += (bytes + 255) & ~(size_t)255;
        return p;
    };
    float* norm   = (float*)alloc((size_t)N_NODES * 4);
    int* deg      = (int*)alloc((size_t)2 * N_NODES * 4);
    int* cnt      = deg + N_NODES;
    int* rowstart = (int*)alloc((size_t)(N_NODES + 1) * 4);
    int* bsums    = (int*)alloc(64 * 4);
    int* esrc     = (int*)alloc((size_t)N_EDGES * 4);
    float* coeffs = (float*)alloc(64 * 4);
    short* Wb     = (short*)alloc((size_t)3 * DIM * DIM * 2);
    float* h      = (float*)alloc((size_t)N_NODES * DIM * 4);
    float* h1     = (float*)alloc((size_t)N_NODES * DIM * 4);

    k_zero_int<<<(2 * N_NODES + 255) / 256, 256, 0, stream>>>(deg, 2 * N_NODES);
    k_deg<<<(N_EDGES + 255) / 256, 256, 0, stream>>>(dst, deg);
    int nchunks = (N_NODES + 1023) / 1024;  // 49
    k_scan1<<<nchunks, 256, 0, stream>>>(deg, rowstart, bsums, norm);
    k_scan2<<<1, 64, 0, stream>>>(bsums, nchunks);
    k_scan3<<<(N_NODES + 255) / 256, 256, 0, stream>>>(bsums, rowstart);
    k_fill<<<(N_EDGES + 255) / 256, 256, 0, stream>>>(src, dst, rowstart, cnt, esrc);
    k_coeffs<<<1, 1, 0, stream>>>(gl, gh, gm, coeffs);
    k_wconv<<<dim3(16, 3), 256, 0, stream>>>(W_low, W_high, W_mid, Wb);

    int spmm_blocks = (N_NODES * 64 + 255) / 256;
    k_spmm<<<spmm_blocks, 256, 0, stream>>>(feature, norm, rowstart, esrc, h);
    k_spmm<<<spmm_blocks, 256, 0, stream>>>(h, norm, rowstart, esrc, h1);

    k_gemm_fused<<<(N_NODES + RT - 1) / RT, 256, 0, stream>>>(
        h, feature, h1, Wb, coeffs, bias, snorm, out);
}

// Round 3
// 251.197 us; speedup vs baseline: 2.1202x; 1.3054x over previous
//
#include <hip/hip_runtime.h>
#include <hip/hip_bf16.h>
#include <math.h>

#define N_NODES 50000
#define N_EDGES 600000
#define DIM 128
#define KGAM 8
#define EPSV 1e-9f

typedef __attribute__((ext_vector_type(8))) short short8;
typedef __attribute__((ext_vector_type(4))) float float4v;

__device__ __forceinline__ float bf2f(short s) {
    unsigned int u = ((unsigned int)(unsigned short)s) << 16;
    return __builtin_bit_cast(float, u);
}
__device__ __forceinline__ short f2bf(float f) {
    return (short)__builtin_bit_cast(unsigned short, __float2bfloat16(f));
}
__device__ __forceinline__ unsigned int pack2(float a, float b) {
    return (unsigned int)(unsigned short)f2bf(a) | ((unsigned int)(unsigned short)f2bf(b) << 16);
}
__device__ __forceinline__ float sigm(float x) { return 1.f / (1.f + __expf(-x)); }

// ---------------- CSR build ----------------
__global__ void k_zero_int(int* __restrict__ p, int n) {
    int i = blockIdx.x * blockDim.x + threadIdx.x;
    if (i < n) p[i] = 0;
}

__global__ void k_deg(const int* __restrict__ dst, int* __restrict__ deg) {
    int e = blockIdx.x * blockDim.x + threadIdx.x;
    if (e < N_EDGES) atomicAdd(&deg[dst[e]], 1);
}

__global__ void k_scan1(const int* __restrict__ deg, int* __restrict__ rowstart,
                        int* __restrict__ bsums, float* __restrict__ norm) {
    __shared__ int s[256];
    int tid = threadIdx.x;
    int i0 = blockIdx.x * 1024 + tid * 4;
    int v[4]; int sum = 0;
#pragma unroll
    for (int c = 0; c < 4; ++c) {
        int i = i0 + c;
        int d = (i < N_NODES) ? deg[i] : 0;
        v[c] = d; sum += d;
    }
    s[tid] = sum; __syncthreads();
#pragma unroll
    for (int off = 1; off < 256; off <<= 1) {
        int t = (tid >= off) ? s[tid - off] : 0;
        __syncthreads();
        s[tid] += t;
        __syncthreads();
    }
    if (tid == 255) bsums[blockIdx.x] = s[255];
    int run = s[tid] - sum;
#pragma unroll
    for (int c = 0; c < 4; ++c) {
        int i = i0 + c;
        if (i < N_NODES) {
            rowstart[i] = run;
            norm[i] = rsqrtf((float)(v[c] < 1 ? 1 : v[c]));
        }
        run += v[c];
    }
}

__global__ void k_scan2(int* __restrict__ bsums, int nb) {
    __shared__ int s[64];
    int tid = threadIdx.x;
    int v = (tid < nb) ? bsums[tid] : 0;
    s[tid] = v; __syncthreads();
#pragma unroll
    for (int off = 1; off < 64; off <<= 1) {
        int t = (tid >= off) ? s[tid - off] : 0;
        __syncthreads();
        s[tid] += t;
        __syncthreads();
    }
    if (tid < nb) bsums[tid] = s[tid] - v;
}

__global__ void k_scan3(const int* __restrict__ bsums, int* __restrict__ rowstart) {
    int i = blockIdx.x * blockDim.x + threadIdx.x;
    if (i < N_NODES) rowstart[i] += bsums[i >> 10];
    if (i == 0) rowstart[N_NODES] = N_EDGES;
}

__global__ void k_fill(const int* __restrict__ src, const int* __restrict__ dst,
                       const int* __restrict__ rowstart, int* __restrict__ cnt,
                       int* __restrict__ esrc) {
    int e = blockIdx.x * blockDim.x + threadIdx.x;
    if (e < N_EDGES) {
        int d = dst[e];
        int slot = rowstart[d] + atomicAdd(&cnt[d], 1);
        esrc[slot] = src[e];
    }
}

// ---------------- blend coefficients ----------------
__global__ void k_coeffs(const float* __restrict__ gl, const float* __restrict__ gh,
                         const float* __restrict__ gm, float* __restrict__ c) {
    if (threadIdx.x == 0 && blockIdx.x == 0) {
        float a0 = 0, b0 = 0, a1 = 0, b1 = 0, sg = 0, m2 = 0;
        for (int k = 0; k < KGAM; ++k) {
            float al = EPSV + (float)k * (1.f - 2.f * EPSV) / (KGAM - 1);
            float md = EPSV + (float)k * (1.f - EPSV) / (KGAM - 1);
            float l = fmaxf(gl[k], 0.f), h = fmaxf(gh[k], 0.f), m = fmaxf(gm[k], 0.f);
            a0 += al * l;  b0 += (1.f - al) * l;
            a1 += -al * h; b1 += (1.f - al) * h;
            sg += m;       m2 += md * m;
        }
        c[0] = a0; c[1] = b0; c[2] = a1; c[3] = b1; c[4] = sg; c[5] = -m2;
    }
}

// ---------------- weights -> bf16 (Wb is 3x128x128 bf16) ----------------
__global__ void k_wconv(const float* __restrict__ W0, const float* __restrict__ W1,
                        const float* __restrict__ W2, unsigned int* __restrict__ Wb) {
    const float* Ws = (blockIdx.y == 0) ? W0 : (blockIdx.y == 1) ? W1 : W2;
    int i = (blockIdx.x * 256 + threadIdx.x) * 4;
    if (i < DIM * DIM) {
        float4 v = *(const float4*)(Ws + i);
        uint2 o; o.x = pack2(v.x, v.y); o.y = pack2(v.z, v.w);
        *(uint2*)(Wb + (blockIdx.y * DIM * DIM + i) / 2) = o;
    }
}

// ---------------- prescale: fb = bf16(feature), fp = bf16(feature*norm) ----------------
__global__ void k_prescale(const float4* __restrict__ f, const float* __restrict__ norm,
                           uint2* __restrict__ fb, uint2* __restrict__ fp) {
    int i = blockIdx.x * 256 + threadIdx.x;          // one float4 group
    if (i >= N_NODES * DIM / 4) return;
    int row = i >> 5;                                // 32 groups per row
    float nv = norm[row];
    float4 v = f[i];
    uint2 a; a.x = pack2(v.x, v.y); a.y = pack2(v.z, v.w);
    uint2 b; b.x = pack2(v.x * nv, v.y * nv); b.y = pack2(v.z * nv, v.w * nv);
    fb[i] = a;
    fp[i] = b;
}

// ---------------- SpMM: 2 nodes per wave (32 lanes x 4 bf16), pre-scaled input ----
// hout[v] = bf16(norm[v] * sum_u in[u]);  preout[v] = bf16(norm[v]^2 * sum) if wpre
__device__ __forceinline__ void acc4(float4& a, uint2 r) {
    a.x += __builtin_bit_cast(float, r.x << 16);
    a.y += __builtin_bit_cast(float, r.x & 0xffff0000u);
    a.z += __builtin_bit_cast(float, r.y << 16);
    a.w += __builtin_bit_cast(float, r.y & 0xffff0000u);
}

__global__ void k_spmm(const uint2* __restrict__ in, const float* __restrict__ norm,
                       const int* __restrict__ rowstart, const int* __restrict__ esrc,
                       uint2* __restrict__ hout, uint2* __restrict__ preout, int wpre) {
    int v = blockIdx.x * 8 + (threadIdx.x >> 5);
    int l = threadIdx.x & 31;
    if (v >= N_NODES) return;
    int beg = rowstart[v], end = rowstart[v + 1];
    float4 acc = {0.f, 0.f, 0.f, 0.f};
    int t = beg;
    for (; t + 3 < end; t += 4) {
        int u0 = esrc[t], u1 = esrc[t + 1], u2 = esrc[t + 2], u3 = esrc[t + 3];
        uint2 r0 = in[(size_t)u0 * 32 + l];
        uint2 r1 = in[(size_t)u1 * 32 + l];
        uint2 r2 = in[(size_t)u2 * 32 + l];
        uint2 r3 = in[(size_t)u3 * 32 + l];
        acc4(acc, r0); acc4(acc, r1); acc4(acc, r2); acc4(acc, r3);
    }
    for (; t < end; ++t) {
        uint2 r = in[(size_t)esrc[t] * 32 + l];
        acc4(acc, r);
    }
    float nv = norm[v];
    float hx = acc.x * nv, hy = acc.y * nv, hz = acc.z * nv, hw = acc.w * nv;
    uint2 o; o.x = pack2(hx, hy); o.y = pack2(hz, hw);
    hout[(size_t)v * 32 + l] = o;
    if (wpre) {
        uint2 p; p.x = pack2(hx * nv, hy * nv); p.y = pack2(hz * nv, hw * nv);
        preout[(size_t)v * 32 + l] = p;
    }
}

// ---------------- fused tri-GEMM + gating (bf16 inputs, 8 waves, ct-split) --------
// A: lane holds A[m=lane&15][k=quad*8+j]; B: lane holds W[n=lane&15][k=quad*8+j];
// C/D: col=lane&15, row=quad*4+reg  (all verified by R1/R2 pass)
#define RT 64
#define TSTR 136

__global__ __launch_bounds__(512, 4) void k_gemm_fused(
    const short* __restrict__ hB, const short* __restrict__ fB,
    const short* __restrict__ h1B, const short* __restrict__ Wb,
    const float* __restrict__ coeffs, const float* __restrict__ bias,
    const float* __restrict__ snorm, float* __restrict__ out) {
    __shared__ short Ts[3][RT * TSTR];

    const float c0 = coeffs[0], c1 = coeffs[1], c2 = coeffs[2];
    const float c3 = coeffs[3], c4 = coeffs[4], c5 = coeffs[5];
    const int r0 = blockIdx.x * RT;
    const int tid = threadIdx.x;

    // stage: blend bf16 h/f/h1 -> bf16 T0,T1,T2 tiles (1024 groups of 8)
#pragma unroll
    for (int it = 0; it < 2; ++it) {
        int idx = tid + it * 512;
        int r = idx >> 4;
        int cg = (idx & 15) * 8;
        int row = r0 + r;
        short8 hv = {0,0,0,0,0,0,0,0}, fv = {0,0,0,0,0,0,0,0}, h1v = {0,0,0,0,0,0,0,0};
        if (row < N_NODES) {
            size_t base = (size_t)row * DIM + cg;
            hv  = *(const short8*)(hB + base);
            fv  = *(const short8*)(fB + base);
            h1v = *(const short8*)(h1B + base);
        }
        short8 t0, t1, t2;
#pragma unroll
        for (int j = 0; j < 8; ++j) {
            float hf = bf2f(hv[j]), ff = bf2f(fv[j]), h1f = bf2f(h1v[j]);
            t0[j] = f2bf(c0 * hf + c1 * ff);
            t1[j] = f2bf(c2 * hf + c3 * ff);
            t2[j] = f2bf(c4 * h1f + c5 * ff);
        }
        int la = r * TSTR + cg;
        *(short8*)&Ts[0][la] = t0;
        *(short8*)&Ts[1][la] = t1;
        *(short8*)&Ts[2][la] = t2;
    }
    __syncthreads();

    const int lane = tid & 63;
    const int ct = tid >> 6;        // wave owns one 16-col tile
    const int m = lane & 15;
    const int quad = lane >> 4;

    float4v acc[3][4];
    const float4v zero = {0.f, 0.f, 0.f, 0.f};
#pragma unroll
    for (int g = 0; g < 3; ++g)
#pragma unroll
        for (int rt = 0; rt < 4; ++rt) acc[g][rt] = zero;

    const short* wbase = Wb + (ct * 16 + m) * DIM + quad * 8;
#pragma unroll
    for (int ks = 0; ks < 4; ++ks) {
        const short* wp = wbase + ks * 32;
        short8 b0 = *(const short8*)(wp);
        short8 b1 = *(const short8*)(wp + DIM * DIM);
        short8 b2 = *(const short8*)(wp + 2 * DIM * DIM);
#pragma unroll
        for (int rt = 0; rt < 4; ++rt) {
            int aoff = (rt * 16 + m) * TSTR + ks * 32 + quad * 8;
            short8 a0 = *(const short8*)&Ts[0][aoff];
            short8 a1 = *(const short8*)&Ts[1][aoff];
            short8 a2 = *(const short8*)&Ts[2][aoff];
            acc[0][rt] = __builtin_amdgcn_mfma_f32_16x16x32_bf16(a0, b0, acc[0][rt], 0, 0, 0);
            acc[1][rt] = __builtin_amdgcn_mfma_f32_16x16x32_bf16(a1, b1, acc[1][rt], 0, 0, 0);
            acc[2][rt] = __builtin_amdgcn_mfma_f32_16x16x32_bf16(a2, b2, acc[2][rt], 0, 0, 0);
        }
    }

    // epilogue: sequential mutual gating + bias + graph-norm + relu
    const int col = ct * 16 + m;
    const float bc = bias[col];
#pragma unroll
    for (int rt = 0; rt < 4; ++rt) {
#pragma unroll
        for (int r = 0; r < 4; ++r) {
            int row = r0 + rt * 16 + quad * 4 + r;
            if (row < N_NODES) {
                float sn = snorm[row];
                float o0 = acc[0][rt][r], o1 = acc[1][rt][r], o2 = acc[2][rt][r];
                float g0 = o0 * sigm(o1 + o2);
                float g1 = o1 * sigm(g0 + o2);
                float g2 = o2 * sigm(g0 + g1);
                float vv = (g0 + g1 + g2 + bc) * sn;
                out[(size_t)row * DIM + col] = fmaxf(vv, 0.f);
            }
        }
    }
}

extern "C" void kernel_launch(void* const* d_in, const int* in_sizes, int n_in,
                              void* d_out, int out_size, void* d_ws, size_t ws_size,
                              hipStream_t stream) {
    const float* feature = (const float*)d_in[0];
    const float* snorm   = (const float*)d_in[1];
    const int*   src     = (const int*)d_in[2];
    const int*   dst     = (const int*)d_in[3];
    const float* W_low   = (const float*)d_in[4];
    const float* W_high  = (const float*)d_in[5];
    const float* W_mid   = (const float*)d_in[6];
    const float* gl      = (const float*)d_in[7];
    const float* gh      = (const float*)d_in[8];
    const float* gm      = (const float*)d_in[9];
    const float* bias    = (const float*)d_in[10];
    float* out = (float*)d_out;

    char* w = (char*)d_ws;
    auto alloc = [&](size_t bytes) {
        char* p = w;
        w += (bytes + 255) & ~(size_t)255;
        return p;
    };
    float* norm   = (float*)alloc((size_t)N_NODES * 4);
    int* deg      = (int*)alloc((size_t)2 * N_NODES * 4);
    int* cnt      = deg + N_NODES;
    int* rowstart = (int*)alloc((size_t)(N_NODES + 1) * 4);
    int* bsums    = (int*)alloc(64 * 4);
    int* esrc     = (int*)alloc((size_t)N_EDGES * 4);
    float* coeffs = (float*)alloc(64 * 4);
    short* Wb     = (short*)alloc((size_t)3 * DIM * DIM * 2);
    short* fb     = (short*)alloc((size_t)N_NODES * DIM * 2);
    short* fp     = (short*)alloc((size_t)N_NODES * DIM * 2);
    short* h      = (short*)alloc((size_t)N_NODES * DIM * 2);
    short* hp     = (short*)alloc((size_t)N_NODES * DIM * 2);
    short* h1     = (short*)alloc((size_t)N_NODES * DIM * 2);

    k_zero_int<<<(2 * N_NODES + 255) / 256, 256, 0, stream>>>(deg, 2 * N_NODES);
    k_deg<<<(N_EDGES + 255) / 256, 256, 0, stream>>>(dst, deg);
    int nchunks = (N_NODES + 1023) / 1024;  // 49
    k_scan1<<<nchunks, 256, 0, stream>>>(deg, rowstart, bsums, norm);
    k_scan2<<<1, 64, 0, stream>>>(bsums, nchunks);
    k_scan3<<<(N_NODES + 255) / 256, 256, 0, stream>>>(bsums, rowstart);
    k_fill<<<(N_EDGES + 255) / 256, 256, 0, stream>>>(src, dst, rowstart, cnt, esrc);
    k_coeffs<<<1, 1, 0, stream>>>(gl, gh, gm, coeffs);
    k_wconv<<<dim3(16, 3), 256, 0, stream>>>(W_low, W_high, W_mid, (unsigned int*)Wb);
    k_prescale<<<(N_NODES * DIM / 4 + 255) / 256, 256, 0, stream>>>(
        (const float4*)feature, norm, (uint2*)fb, (uint2*)fp);

    int spmm_blocks = (N_NODES + 7) / 8;
    k_spmm<<<spmm_blocks, 256, 0, stream>>>((const uint2*)fp, norm, rowstart, esrc,
                                            (uint2*)h, (uint2*)hp, 1);
    k_spmm<<<spmm_blocks, 256, 0, stream>>>((const uint2*)hp, norm, rowstart, esrc,
                                            (uint2*)h1, (uint2*)hp, 0);

    k_gemm_fused<<<(N_NODES + RT - 1) / RT, 512, 0, stream>>>(
        h, fb, h1, Wb, coeffs, bias, snorm, out);
}